// Round 7
// baseline (89.019 us; speedup 1.0000x reference)
//
#include <hip/hip_runtime.h>
#include <cstdint>

// AttentionFlow — fused MFMA; 16-row tiles, launch-skew pipelining,
// XCD-batch pinning, slot0 written during staging.
// B=8, T=2048, I=512, D=512. Output (B,T,4D) fp32.

constexpr int kB = 8;
constexpr int kT = 2048;
constexpr int kI = 512;
constexpr int kD = 512;
constexpr int kW = 4 * kD;

constexpr int kSplit = 32;
constexpr int kTchunk = kT / kSplit;  // 64

using f32x4  = __attribute__((ext_vector_type(4))) float;
using bf16x4 = __attribute__((ext_vector_type(4))) __bf16;
using bf16x8 = __attribute__((ext_vector_type(8))) __bf16;

__device__ __forceinline__ float wave_max(float v) {
#pragma unroll
  for (int off = 32; off > 0; off >>= 1) v = fmaxf(v, __shfl_xor(v, off, 64));
  return v;
}
__device__ __forceinline__ float wave_sum(float v) {
#pragma unroll
  for (int off = 32; off > 0; off >>= 1) v += __shfl_xor(v, off, 64);
  return v;
}
__device__ __forceinline__ float dot8(const f32x4& a0, const f32x4& a1,
                                      const f32x4& b0, const f32x4& b1) {
  return a0.x * b0.x + a0.y * b0.y + a0.z * b0.z + a0.w * b0.w +
         a1.x * b1.x + a1.y * b1.y + a1.z * b1.z + a1.w * b1.w;
}

// qf[((b*32+g)*16+kk)*512 + lane*8 + j] = bf16(q[b][g*16+(lane&15)]
//                                               [kk*32+(lane>>4)*8+j])
__global__ __launch_bounds__(256) void prep_qf_kernel(
    const float* __restrict__ q, const float* __restrict__ w_q,
    const float* __restrict__ b_q, float* __restrict__ sq,
    __bf16* __restrict__ qf) {
  __shared__ float sacc[16][17];
  const int b = blockIdx.y;
  const int g = blockIdx.x;  // 0..31
  const int tid = threadIdx.x;
  const int kk0 = tid >> 6;
  const int lane = tid & 63;
  const int lr = lane & 15, lg = lane >> 4;
  const float* row = q + ((size_t)(b * kI + g * 16 + lr)) * kD;
  float sp = 0.f;
#pragma unroll
  for (int kk = kk0; kk < 16; kk += 4) {
    const int ka = kk * 32 + lg * 8;
    f32x4 v0 = *(const f32x4*)(row + ka);
    f32x4 v1 = *(const f32x4*)(row + ka + 4);
    f32x4 u0 = *(const f32x4*)(w_q + ka);
    f32x4 u1 = *(const f32x4*)(w_q + ka + 4);
    sp += dot8(v0, v1, u0, u1);
    bf16x8 o = {(__bf16)v0.x, (__bf16)v0.y, (__bf16)v0.z, (__bf16)v0.w,
                (__bf16)v1.x, (__bf16)v1.y, (__bf16)v1.z, (__bf16)v1.w};
    *(bf16x8*)(qf + ((((size_t)(b * 32 + g)) * 16 + kk) << 9) + lane * 8) = o;
  }
  sacc[lr][kk0 * 4 + lg] = sp;
  __syncthreads();
  if (tid < 16) {
    float s = 0.f;
#pragma unroll
    for (int j = 0; j < 16; ++j) s += sacc[tid][j];
    sq[b * kI + g * 16 + tid] = s + b_q[0];
  }
}

// vf[((b*32+gd)*16+kki)*512 + lane*8 + j] = bf16(q[b][kki*32+(lane>>4)*8+j]
//                                                 [gd*16+(lane&15)])
__global__ __launch_bounds__(256) void prep_vf_kernel(
    const float* __restrict__ q, __bf16* __restrict__ vf) {
  __shared__ float ts[64][68];
  const int b = blockIdx.z;
  const int i0 = blockIdx.x * 64;
  const int d0 = blockIdx.y * 64;
  const int tid = threadIdx.x;
  const int r = tid >> 2;
  const int cg = (tid & 3) * 16;
#pragma unroll
  for (int j = 0; j < 4; ++j) {
    f32x4 v = *(const f32x4*)(q + ((size_t)(b * kI + i0 + r)) * kD + d0 + cg + 4 * j);
    ts[r][cg + 4 * j + 0] = v.x;
    ts[r][cg + 4 * j + 1] = v.y;
    ts[r][cg + 4 * j + 2] = v.z;
    ts[r][cg + 4 * j + 3] = v.w;
  }
  __syncthreads();
  const int dl = tid >> 2;
  const int ig = (tid & 3) * 16;
  bf16x8 o0, o1;
#pragma unroll
  for (int j = 0; j < 8; ++j) o0[j] = (__bf16)ts[ig + j][dl];
#pragma unroll
  for (int j = 0; j < 8; ++j) o1[j] = (__bf16)ts[ig + 8 + j][dl];
  const int gd = (d0 >> 4) + (dl >> 4);
  const int lr = dl & 15;
  const int kki0 = (i0 >> 5) + (ig >> 5);
  const int lg0 = (ig & 31) >> 3;
  const int i1 = ig + 8;
  const int kki1 = (i0 >> 5) + (i1 >> 5);
  const int lg1 = (i1 & 31) >> 3;
  *(bf16x8*)(vf + ((((size_t)(b * 32 + gd)) * 16 + kki0) << 9) +
             (lg0 * 16 + lr) * 8) = o0;
  *(bf16x8*)(vf + ((((size_t)(b * 32 + gd)) * 16 + kki1) << 9) +
             (lg1 * 16 + lr) * 8) = o1;
}

__global__ __launch_bounds__(512, 4) void fused_attn(
    const float* __restrict__ c, const __bf16* __restrict__ qf,
    const __bf16* __restrict__ vf, const float* __restrict__ w_cq,
    const float* __restrict__ w_c, const float* __restrict__ b_c,
    const float* __restrict__ b_cq, const float* __restrict__ sq,
    float* __restrict__ out, float* __restrict__ mrow) {
  // lAP: 16 k-chunks x 16 rows x 72B. Holds A (phase 1), then P (phase 2).
  __shared__ __align__(16) char lAP[16 * 1152];
  __shared__ float scrow[16];
  __shared__ float redm[128];
  __shared__ float reds[128];

  const int bid = blockIdx.x;
  const int b = bid & 7;           // batch == XCD (8 XCDs, grid%8==0)
  const int t0 = (bid >> 3) * 16;
  const int tid = threadIdx.x;
  const int w = tid >> 6;  // 0..7: 64-wide i (phase1) / d (phase2) slice
  const int lane = tid & 63;
  const int lr = lane & 15, lg = lane >> 4;

  // ---- stage A = bf16(c .* w_cq) -> lAP; write slot0; sc rowdot folded ---
  {
    const int srow = tid >> 5;       // 0..15
    const int col4 = (tid & 31) * 4; // 0..124
    const float* crow = c + ((size_t)(b * kT + t0 + srow)) * kD;
    float* orow0 = out + ((size_t)(b * kT + t0 + srow)) * kW;
    float scp = 0.f;
#pragma unroll
    for (int j = 0; j < 4; ++j) {
      const int col = col4 + j * 128;
      f32x4 v = *(const f32x4*)(crow + col);
      *(f32x4*)(orow0 + col) = v;  // slot0 = c (early write)
      const f32x4 wq = *(const f32x4*)(w_cq + col);
      const f32x4 wc = *(const f32x4*)(w_c + col);
      scp += v.x * wc.x + v.y * wc.y + v.z * wc.z + v.w * wc.w;
      v *= wq;
      bf16x4 bv = {(__bf16)v.x, (__bf16)v.y, (__bf16)v.z, (__bf16)v.w};
      *(bf16x4*)(lAP + (col >> 5) * 1152 + srow * 72 + (col & 31) * 2) = bv;
    }
    scp += __shfl_xor(scp, 1, 64);
    scp += __shfl_xor(scp, 2, 64);
    scp += __shfl_xor(scp, 4, 64);
    scp += __shfl_xor(scp, 8, 64);
    scp += __shfl_xor(scp, 16, 64);
    if ((tid & 31) == 0) scrow[srow] = scp + b_c[0];
  }
  __syncthreads();

  // ---------------- Phase 1: S = A @ qf (LDS A, prefetched B) ------------
  const __bf16* qfb = qf + (((size_t)(b * 32 + w * 4)) * 16 << 9) + lane * 8;
  f32x4 acc[4] = {};
  bf16x8 bcur[4], bnxt[4];
#pragma unroll
  for (int n4 = 0; n4 < 4; ++n4)
    bcur[n4] = *(const bf16x8*)(qfb + (((size_t)(n4 * 16)) << 9));
#pragma unroll
  for (int kk = 0; kk < 16; ++kk) {
    if (kk < 15) {
#pragma unroll
      for (int n4 = 0; n4 < 4; ++n4)
        bnxt[n4] = *(const bf16x8*)(qfb + (((size_t)(n4 * 16 + kk + 1)) << 9));
    }
    const bf16x8 a0 = *(const bf16x8*)(lAP + kk * 1152 + lr * 72 + lg * 16);
#pragma unroll
    for (int n4 = 0; n4 < 4; ++n4)
      acc[n4] = __builtin_amdgcn_mfma_f32_16x16x32_bf16(a0, bcur[n4], acc[n4], 0, 0, 0);
#pragma unroll
    for (int n4 = 0; n4 < 4; ++n4) bcur[n4] = bnxt[n4];
  }

  // biases
  const float bq = b_cq[0];
  float sqv[4];
#pragma unroll
  for (int n4 = 0; n4 < 4; ++n4) sqv[n4] = sq[b * kI + w * 64 + n4 * 16 + lr];
  float scr[4];
#pragma unroll
  for (int r = 0; r < 4; ++r) scr[r] = scrow[lg * 4 + r] + bq;
#pragma unroll
  for (int n4 = 0; n4 < 4; ++n4)
#pragma unroll
    for (int r = 0; r < 4; ++r) acc[n4][r] += scr[r] + sqv[n4];

  // ---------------- exact softmax over i (512) ---------------------------
  float mx[4];
#pragma unroll
  for (int r = 0; r < 4; ++r) {
    float v = acc[0][r];
#pragma unroll
    for (int n4 = 1; n4 < 4; ++n4) v = fmaxf(v, acc[n4][r]);
#pragma unroll
    for (int off = 1; off <= 8; off <<= 1) v = fmaxf(v, __shfl_xor(v, off, 64));
    mx[r] = v;
  }
  if (lr == 0) {
#pragma unroll
    for (int r = 0; r < 4; ++r) redm[w * 16 + lg * 4 + r] = mx[r];
  }
  __syncthreads();
#pragma unroll
  for (int r = 0; r < 4; ++r) {
    const int rw = lg * 4 + r;
    float v = redm[rw];
#pragma unroll
    for (int w2 = 1; w2 < 8; ++w2) v = fmaxf(v, redm[w2 * 16 + rw]);
    mx[r] = v;
  }
  if (w == 0 && lr == 0) {
#pragma unroll
    for (int r = 0; r < 4; ++r) mrow[b * kT + t0 + lg * 4 + r] = mx[r];
  }

  float sm[4] = {};
#pragma unroll
  for (int n4 = 0; n4 < 4; ++n4)
#pragma unroll
    for (int r = 0; r < 4; ++r) {
      const float p = __expf(acc[n4][r] - mx[r]);
      acc[n4][r] = p;
      sm[r] += p;
    }
#pragma unroll
  for (int r = 0; r < 4; ++r)
#pragma unroll
    for (int off = 1; off <= 8; off <<= 1) sm[r] += __shfl_xor(sm[r], off, 64);
  if (lr == 0) {
#pragma unroll
    for (int r = 0; r < 4; ++r) reds[w * 16 + lg * 4 + r] = sm[r];
  }
  __syncthreads();
  float inv[4];
#pragma unroll
  for (int r = 0; r < 4; ++r) {
    const int rw = lg * 4 + r;
    float v = reds[rw];
#pragma unroll
    for (int w2 = 1; w2 < 8; ++w2) v += reds[w2 * 16 + rw];
    inv[r] = 1.f / v;
  }

  // -------- prefetch phase-2 first B frags (overlap with P publish) ------
  const __bf16* vfb = vf + (((size_t)(b * 32 + w * 4)) * 16 << 9) + lane * 8;
  bf16x8 vcur[4], vnxt[4];
#pragma unroll
  for (int n4 = 0; n4 < 4; ++n4)
    vcur[n4] = *(const bf16x8*)(vfb + (((size_t)(n4 * 16)) << 9));

  // ---------------- P (bf16) -> lAP (aliases A), k-chunked ---------------
#pragma unroll
  for (int r = 0; r < 4; ++r) {
    const int trow = lg * 4 + r;
#pragma unroll
    for (int n4 = 0; n4 < 4; ++n4) {
      const int icol = w * 64 + n4 * 16 + lr;
      const int kkc = icol >> 5, kc = icol & 31;
      *(__bf16*)(lAP + kkc * 1152 + trow * 72 + kc * 2) =
          (__bf16)(acc[n4][r] * inv[r]);
    }
  }
  __syncthreads();

  // ---------------- Phase 2: O = P @ vf (LDS A, prefetched B) ------------
  f32x4 o[4] = {};
#pragma unroll
  for (int kki = 0; kki < 16; ++kki) {
    if (kki < 15) {
#pragma unroll
      for (int n4 = 0; n4 < 4; ++n4)
        vnxt[n4] = *(const bf16x8*)(vfb + (((size_t)(n4 * 16 + kki + 1)) << 9));
    }
    const bf16x8 a0 = *(const bf16x8*)(lAP + kki * 1152 + lr * 72 + lg * 16);
#pragma unroll
    for (int n4 = 0; n4 < 4; ++n4)
      o[n4] = __builtin_amdgcn_mfma_f32_16x16x32_bf16(a0, vcur[n4], o[n4], 0, 0, 0);
#pragma unroll
    for (int n4 = 0; n4 < 4; ++n4) vcur[n4] = vnxt[n4];
  }

  // ---------------- epilogue: slots [c2q | c*c2q] ------------------------
#pragma unroll
  for (int r = 0; r < 4; ++r) {
    const int t = t0 + lg * 4 + r;
    const size_t rb = (size_t)(b * kT + t);
    const float* crow = c + rb * kD;
    float* orow = out + rb * kW;
#pragma unroll
    for (int n4 = 0; n4 < 4; ++n4) {
      const int d = w * 64 + n4 * 16 + lr;
      const float cvv = crow[d];
      const float pv = o[n4][r];
      orow[kD + d] = pv;
      orow[2 * kD + d] = cvv * pv;
    }
  }
}

__global__ __launch_bounds__(1024) void t_softmax_kernel(
    const float* __restrict__ mrow, float* __restrict__ bw) {
  const int b = blockIdx.x;
  const int tid = threadIdx.x;
  const float v0 = mrow[b * kT + tid], v1 = mrow[b * kT + tid + 1024];
  __shared__ float redm[16];
  __shared__ float reds[16];
  const int wave = tid >> 6, lane = tid & 63;
  float mx = wave_max(fmaxf(v0, v1));
  if (lane == 0) redm[wave] = mx;
  __syncthreads();
  mx = redm[0];
#pragma unroll
  for (int i = 1; i < 16; ++i) mx = fmaxf(mx, redm[i]);
  const float e0 = __expf(v0 - mx), e1 = __expf(v1 - mx);
  float sm = wave_sum(e0 + e1);
  if (lane == 0) reds[wave] = sm;
  __syncthreads();
  sm = 0.f;
#pragma unroll
  for (int i = 0; i < 16; ++i) sm += reds[i];
  const float inv = 1.f / sm;
  bw[b * kT + tid] = e0 * inv;
  bw[b * kT + tid + 1024] = e1 * inv;
}

__global__ __launch_bounds__(256) void q2c_part_kernel(
    const float* __restrict__ c, const float* __restrict__ bw,
    float* __restrict__ part) {
  const int b = blockIdx.y;
  const int sp = blockIdx.x;
  const int tid = threadIdx.x;
  const int d0 = tid, d1 = tid + 256;
  float a0 = 0.f, a1 = 0.f;
  const int tbase = sp * kTchunk;
  for (int t = 0; t < kTchunk; ++t) {
    const float w = bw[b * kT + tbase + t];
    const float* crow = c + ((size_t)b * kT + tbase + t) * kD;
    a0 += w * crow[d0];
    a1 += w * crow[d1];
  }
  part[((size_t)b * kSplit + sp) * kD + d0] = a0;
  part[((size_t)b * kSplit + sp) * kD + d1] = a1;
}

__global__ __launch_bounds__(512) void q2c_reduce_kernel(
    const float* __restrict__ part, float* __restrict__ q2c) {
  const int b = blockIdx.x;
  const int d = threadIdx.x;
  float s = 0.f;
#pragma unroll
  for (int p = 0; p < kSplit; ++p) s += part[((size_t)b * kSplit + p) * kD + d];
  q2c[b * kD + d] = s;
}

__global__ __launch_bounds__(128) void slot3_kernel(
    const float* __restrict__ c, const float* __restrict__ q2c,
    float* __restrict__ out) {
  const int row = blockIdx.x;  // b*kT + t
  const int b = row >> 11;
  const int x4 = threadIdx.x * 4;
  f32x4 cv = *(const f32x4*)(c + (size_t)row * kD + x4);
  f32x4 qc = *(const f32x4*)(q2c + b * kD + x4);
  *(f32x4*)(out + (size_t)row * kW + 3 * kD + x4) = cv * qc;
}

extern "C" void kernel_launch(void* const* d_in, const int* in_sizes, int n_in,
                              void* d_out, int out_size, void* d_ws, size_t ws_size,
                              hipStream_t stream) {
  const float* c    = (const float*)d_in[0];
  const float* q    = (const float*)d_in[1];
  const float* w_c  = (const float*)d_in[2];
  const float* b_c  = (const float*)d_in[3];
  const float* w_q  = (const float*)d_in[4];
  const float* b_q  = (const float*)d_in[5];
  const float* w_cq = (const float*)d_in[6];
  const float* b_cq = (const float*)d_in[7];
  float* out = (float*)d_out;
  float* ws = (float*)d_ws;

  // ws layout (floats): sq 4096 | mrow 16384 | bw 16384 | part 131072 |
  //                     q2c 4096; then bf16: qf 2M | vf 2M  (~8.7 MB)
  float* sq   = ws;
  float* mrow = sq + kB * kI;
  float* bw   = mrow + kB * kT;
  float* part = bw + kB * kT;
  float* q2c  = part + (size_t)kB * kSplit * kD;
  __bf16* qf = (__bf16*)(q2c + kB * kD);
  __bf16* vf = qf + (size_t)kB * kI * kD;

  dim3 gpq(kI / 16, kB);
  prep_qf_kernel<<<gpq, 256, 0, stream>>>(q, w_q, b_q, sq, qf);
  dim3 gpv(kI / 64, kD / 64, kB);
  prep_vf_kernel<<<gpv, 256, 0, stream>>>(q, vf);

  // 1D grid: bid = tile*8 + batch  (batch == XCD; 1024 % 8 == 0, bijective)
  fused_attn<<<kB * (kT / 16), 512, 0, stream>>>(c, qf, vf, w_cq, w_c, b_c,
                                                 b_cq, sq, out, mrow);

  t_softmax_kernel<<<kB, 1024, 0, stream>>>(mrow, bw);
  dim3 gq(kSplit, kB);
  q2c_part_kernel<<<gq, 256, 0, stream>>>(c, bw, part);
  q2c_reduce_kernel<<<kB, 512, 0, stream>>>(part, q2c);

  slot3_kernel<<<kB * kT, 128, 0, stream>>>(c, q2c, out);
}

// Round 8
// 73.791 us; speedup vs baseline: 1.2064x; 1.2064x over previous
//
#include <hip/hip_runtime.h>
#include <cstdint>

// AttentionFlow — fused MFMA; 64-row tiles (high B-reuse), 2-deep B prefetch,
// q2c partials fused into epilogue, flash-merge tail.
// B=8, T=2048, I=512, D=512. Output (B,T,4D) fp32.

constexpr int kB = 8;
constexpr int kT = 2048;
constexpr int kI = 512;
constexpr int kD = 512;
constexpr int kW = 4 * kD;
constexpr int kRows = 64;                // t-rows per block
constexpr int kTiles = kT / kRows;       // 32 tiles per batch
constexpr int kChunk = kRows * 72;       // LDS bytes per k-chunk (4608)

using f32x4  = __attribute__((ext_vector_type(4))) float;
using bf16x4 = __attribute__((ext_vector_type(4))) __bf16;
using bf16x8 = __attribute__((ext_vector_type(8))) __bf16;

__device__ __forceinline__ float wave_sum(float v) {
#pragma unroll
  for (int off = 32; off > 0; off >>= 1) v += __shfl_xor(v, off, 64);
  return v;
}
__device__ __forceinline__ float dot8(const f32x4& a0, const f32x4& a1,
                                      const f32x4& b0, const f32x4& b1) {
  return a0.x * b0.x + a0.y * b0.y + a0.z * b0.z + a0.w * b0.w +
         a1.x * b1.x + a1.y * b1.y + a1.z * b1.z + a1.w * b1.w;
}

// qf[((b*32+g)*16+kk)*512 + lane*8 + j] = bf16(q[b][g*16+(lane&15)]
//                                               [kk*32+(lane>>4)*8+j]) + sq
__global__ __launch_bounds__(256) void prep_qf_kernel(
    const float* __restrict__ q, const float* __restrict__ w_q,
    const float* __restrict__ b_q, float* __restrict__ sq,
    __bf16* __restrict__ qf) {
  __shared__ float sacc[16][17];
  const int b = blockIdx.y;
  const int g = blockIdx.x;  // 0..31
  const int tid = threadIdx.x;
  const int kk0 = tid >> 6;
  const int lane = tid & 63;
  const int lr = lane & 15, lg = lane >> 4;
  const float* row = q + ((size_t)(b * kI + g * 16 + lr)) * kD;
  float sp = 0.f;
#pragma unroll
  for (int kk = kk0; kk < 16; kk += 4) {
    const int ka = kk * 32 + lg * 8;
    f32x4 v0 = *(const f32x4*)(row + ka);
    f32x4 v1 = *(const f32x4*)(row + ka + 4);
    f32x4 u0 = *(const f32x4*)(w_q + ka);
    f32x4 u1 = *(const f32x4*)(w_q + ka + 4);
    sp += dot8(v0, v1, u0, u1);
    bf16x8 o = {(__bf16)v0.x, (__bf16)v0.y, (__bf16)v0.z, (__bf16)v0.w,
                (__bf16)v1.x, (__bf16)v1.y, (__bf16)v1.z, (__bf16)v1.w};
    *(bf16x8*)(qf + ((((size_t)(b * 32 + g)) * 16 + kk) << 9) + lane * 8) = o;
  }
  sacc[lr][kk0 * 4 + lg] = sp;
  __syncthreads();
  if (tid < 16) {
    float s = 0.f;
#pragma unroll
    for (int j = 0; j < 16; ++j) s += sacc[tid][j];
    sq[b * kI + g * 16 + tid] = s + b_q[0];
  }
}

// vf[((b*32+gd)*16+kki)*512 + lane*8 + j] = bf16(q[b][kki*32+(lane>>4)*8+j]
//                                                 [gd*16+(lane&15)])
__global__ __launch_bounds__(256) void prep_vf_kernel(
    const float* __restrict__ q, __bf16* __restrict__ vf) {
  __shared__ float ts[64][68];
  const int b = blockIdx.z;
  const int i0 = blockIdx.x * 64;
  const int d0 = blockIdx.y * 64;
  const int tid = threadIdx.x;
  const int r = tid >> 2;
  const int cg = (tid & 3) * 16;
#pragma unroll
  for (int j = 0; j < 4; ++j) {
    f32x4 v = *(const f32x4*)(q + ((size_t)(b * kI + i0 + r)) * kD + d0 + cg + 4 * j);
    ts[r][cg + 4 * j + 0] = v.x;
    ts[r][cg + 4 * j + 1] = v.y;
    ts[r][cg + 4 * j + 2] = v.z;
    ts[r][cg + 4 * j + 3] = v.w;
  }
  __syncthreads();
  const int dl = tid >> 2;
  const int ig = (tid & 3) * 16;
  bf16x8 o0, o1;
#pragma unroll
  for (int j = 0; j < 8; ++j) o0[j] = (__bf16)ts[ig + j][dl];
#pragma unroll
  for (int j = 0; j < 8; ++j) o1[j] = (__bf16)ts[ig + 8 + j][dl];
  const int gd = (d0 >> 4) + (dl >> 4);
  const int lr = dl & 15;
  const int kki0 = (i0 >> 5) + (ig >> 5);
  const int lg0 = (ig & 31) >> 3;
  const int i1 = ig + 8;
  const int kki1 = (i0 >> 5) + (i1 >> 5);
  const int lg1 = (i1 & 31) >> 3;
  *(bf16x8*)(vf + ((((size_t)(b * 32 + gd)) * 16 + kki0) << 9) +
             (lg0 * 16 + lr) * 8) = o0;
  *(bf16x8*)(vf + ((((size_t)(b * 32 + gd)) * 16 + kki1) << 9) +
             (lg1 * 16 + lr) * 8) = o1;
}

__global__ __launch_bounds__(512, 2) void fused_attn(
    const float* __restrict__ c, const __bf16* __restrict__ qf,
    const __bf16* __restrict__ vf, const float* __restrict__ w_cq,
    const float* __restrict__ w_c, const float* __restrict__ b_c,
    const float* __restrict__ b_cq, const float* __restrict__ sq,
    float* __restrict__ out, float* __restrict__ mz,
    float* __restrict__ u_tile) {
  // lAP: 16 k-chunks x 64 rows x 72B (A in phase 1, P in phase 2) = 73728 B
  __shared__ __align__(16) char lAP[16 * kChunk];
  __shared__ float scrow[kRows];
  __shared__ float redm[8 * kRows];
  __shared__ float reds[8 * kRows];

  const int b = blockIdx.y;
  const int tile = blockIdx.x;
  const int t0 = tile * kRows;
  const int tid = threadIdx.x;
  const int w = tid >> 6;  // 0..7: 64-wide i (phase1) / d (phase2) slice
  const int lane = tid & 63;
  const int lr = lane & 15, lg = lane >> 4;

  // ---- stage A = bf16(c .* w_cq) -> lAP; sc rowdot folded ---------------
  {
    const int srow = tid >> 3;       // 0..63
    const int col4 = (tid & 7) * 4;  // 0..28
    const float* crow = c + ((size_t)(b * kT + t0 + srow)) * kD;
    float scp = 0.f;
#pragma unroll
    for (int j = 0; j < 16; ++j) {
      const int col = col4 + j * 32;
      f32x4 v = *(const f32x4*)(crow + col);
      const f32x4 wq = *(const f32x4*)(w_cq + col);
      const f32x4 wc = *(const f32x4*)(w_c + col);
      scp += v.x * wc.x + v.y * wc.y + v.z * wc.z + v.w * wc.w;
      v *= wq;
      bf16x4 bv = {(__bf16)v.x, (__bf16)v.y, (__bf16)v.z, (__bf16)v.w};
      *(bf16x4*)(lAP + j * kChunk + srow * 72 + col4 * 2) = bv;
    }
    scp += __shfl_xor(scp, 1, 64);
    scp += __shfl_xor(scp, 2, 64);
    scp += __shfl_xor(scp, 4, 64);
    if ((tid & 7) == 0) scrow[srow] = scp + b_c[0];
  }
  __syncthreads();

  // ---------------- Phase 1: S = A @ qf (LDS A, 2-deep prefetch) ---------
  const __bf16* qfb = qf + (((size_t)(b * 32 + w * 4)) * 16 << 9) + lane * 8;
  f32x4 acc[4][4] = {};
  bf16x8 b0[4], b1[4], b2[4];
#pragma unroll
  for (int n4 = 0; n4 < 4; ++n4)
    b0[n4] = *(const bf16x8*)(qfb + (((size_t)(n4 * 16 + 0)) << 9));
#pragma unroll
  for (int n4 = 0; n4 < 4; ++n4)
    b1[n4] = *(const bf16x8*)(qfb + (((size_t)(n4 * 16 + 1)) << 9));
#pragma unroll
  for (int kk = 0; kk < 16; ++kk) {
    if (kk < 14) {
#pragma unroll
      for (int n4 = 0; n4 < 4; ++n4)
        b2[n4] = *(const bf16x8*)(qfb + (((size_t)(n4 * 16 + kk + 2)) << 9));
    }
    bf16x8 af[4];
#pragma unroll
    for (int m = 0; m < 4; ++m)
      af[m] = *(const bf16x8*)(lAP + kk * kChunk + (m * 16 + lr) * 72 + lg * 16);
#pragma unroll
    for (int m = 0; m < 4; ++m)
#pragma unroll
      for (int n4 = 0; n4 < 4; ++n4)
        acc[m][n4] = __builtin_amdgcn_mfma_f32_16x16x32_bf16(af[m], b0[n4],
                                                             acc[m][n4], 0, 0, 0);
#pragma unroll
    for (int n4 = 0; n4 < 4; ++n4) {
      b0[n4] = b1[n4];
      b1[n4] = b2[n4];
    }
  }

  // biases
  const float bq = b_cq[0];
  float sqv[4];
#pragma unroll
  for (int n4 = 0; n4 < 4; ++n4) sqv[n4] = sq[b * kI + w * 64 + n4 * 16 + lr];
  float scr[4][4];
#pragma unroll
  for (int m = 0; m < 4; ++m)
#pragma unroll
    for (int r = 0; r < 4; ++r) scr[m][r] = scrow[m * 16 + lg * 4 + r] + bq;
#pragma unroll
  for (int m = 0; m < 4; ++m)
#pragma unroll
    for (int n4 = 0; n4 < 4; ++n4)
#pragma unroll
      for (int r = 0; r < 4; ++r) acc[m][n4][r] += scr[m][r] + sqv[n4];

  // ---------------- exact softmax over i (512) ---------------------------
  float mx[4][4];
#pragma unroll
  for (int m = 0; m < 4; ++m)
#pragma unroll
    for (int r = 0; r < 4; ++r) {
      float v = acc[m][0][r];
#pragma unroll
      for (int n4 = 1; n4 < 4; ++n4) v = fmaxf(v, acc[m][n4][r]);
#pragma unroll
      for (int off = 1; off <= 8; off <<= 1) v = fmaxf(v, __shfl_xor(v, off, 64));
      mx[m][r] = v;
    }
  if (lr == 0) {
#pragma unroll
    for (int m = 0; m < 4; ++m)
#pragma unroll
      for (int r = 0; r < 4; ++r)
        redm[w * kRows + m * 16 + lg * 4 + r] = mx[m][r];
  }
  __syncthreads();
#pragma unroll
  for (int m = 0; m < 4; ++m)
#pragma unroll
    for (int r = 0; r < 4; ++r) {
      const int rw = m * 16 + lg * 4 + r;
      float v = redm[rw];
#pragma unroll
      for (int w2 = 1; w2 < 8; ++w2) v = fmaxf(v, redm[w2 * kRows + rw]);
      mx[m][r] = v;
    }

  float sm[4][4] = {};
#pragma unroll
  for (int m = 0; m < 4; ++m)
#pragma unroll
    for (int n4 = 0; n4 < 4; ++n4)
#pragma unroll
      for (int r = 0; r < 4; ++r) {
        const float p = __expf(acc[m][n4][r] - mx[m][r]);
        acc[m][n4][r] = p;
        sm[m][r] += p;
      }
#pragma unroll
  for (int m = 0; m < 4; ++m)
#pragma unroll
    for (int r = 0; r < 4; ++r)
#pragma unroll
      for (int off = 1; off <= 8; off <<= 1)
        sm[m][r] += __shfl_xor(sm[m][r], off, 64);
  if (lr == 0) {
#pragma unroll
    for (int m = 0; m < 4; ++m)
#pragma unroll
      for (int r = 0; r < 4; ++r)
        reds[w * kRows + m * 16 + lg * 4 + r] = sm[m][r];
  }
  __syncthreads();
  float inv[4][4];
#pragma unroll
  for (int m = 0; m < 4; ++m)
#pragma unroll
    for (int r = 0; r < 4; ++r) {
      const int rw = m * 16 + lg * 4 + r;
      float v = reds[rw];
#pragma unroll
      for (int w2 = 1; w2 < 8; ++w2) v += reds[w2 * kRows + rw];
      inv[m][r] = 1.f / v;
    }

  // -------- prefetch phase-2 first B frags (overlap with P publish) ------
  const __bf16* vfb = vf + (((size_t)(b * 32 + w * 4)) * 16 << 9) + lane * 8;
  bf16x8 v0_[4], v1_[4], v2_[4];
#pragma unroll
  for (int n4 = 0; n4 < 4; ++n4)
    v0_[n4] = *(const bf16x8*)(vfb + (((size_t)(n4 * 16 + 0)) << 9));
#pragma unroll
  for (int n4 = 0; n4 < 4; ++n4)
    v1_[n4] = *(const bf16x8*)(vfb + (((size_t)(n4 * 16 + 1)) << 9));

  // ---------------- P (bf16) -> lAP (aliases A), k-chunked ---------------
#pragma unroll
  for (int m = 0; m < 4; ++m)
#pragma unroll
    for (int r = 0; r < 4; ++r) {
      const int trow = m * 16 + lg * 4 + r;
#pragma unroll
      for (int n4 = 0; n4 < 4; ++n4) {
        const int icol = w * 64 + n4 * 16 + lr;
        const int kkc = icol >> 5, kc = icol & 31;
        *(__bf16*)(lAP + kkc * kChunk + trow * 72 + kc * 2) =
            (__bf16)(acc[m][n4][r] * inv[m][r]);
      }
    }
  __syncthreads();

  // ---------------- Phase 2: O = P @ vf (LDS A, 2-deep prefetch) ---------
  f32x4 o[4][4] = {};
#pragma unroll
  for (int kki = 0; kki < 16; ++kki) {
    if (kki < 14) {
#pragma unroll
      for (int n4 = 0; n4 < 4; ++n4)
        v2_[n4] = *(const bf16x8*)(vfb + (((size_t)(n4 * 16 + kki + 2)) << 9));
    }
    bf16x8 af[4];
#pragma unroll
    for (int m = 0; m < 4; ++m)
      af[m] = *(const bf16x8*)(lAP + kki * kChunk + (m * 16 + lr) * 72 + lg * 16);
#pragma unroll
    for (int m = 0; m < 4; ++m)
#pragma unroll
      for (int n4 = 0; n4 < 4; ++n4)
        o[m][n4] = __builtin_amdgcn_mfma_f32_16x16x32_bf16(af[m], v0_[n4],
                                                           o[m][n4], 0, 0, 0);
#pragma unroll
    for (int n4 = 0; n4 < 4; ++n4) {
      v0_[n4] = v1_[n4];
      v1_[n4] = v2_[n4];
    }
  }

  // ---- epilogue: slots [c | c2q | c*c2q]; fused q2c partials ------------
  // m_tile = max over rows of mx (identical on all threads after reduce)
  float m_tile;
  {
    float v = mx[0][0];
#pragma unroll
    for (int m = 0; m < 4; ++m)
#pragma unroll
      for (int r = 0; r < 4; ++r) v = fmaxf(v, mx[m][r]);
    v = fmaxf(v, __shfl_xor(v, 16, 64));
    v = fmaxf(v, __shfl_xor(v, 32, 64));
    m_tile = v;
  }
  float u[4] = {};
  float zz = 0.f;
#pragma unroll
  for (int m = 0; m < 4; ++m)
#pragma unroll
    for (int r = 0; r < 4; ++r) {
      const int t = t0 + m * 16 + lg * 4 + r;
      const size_t rb = (size_t)(b * kT + t);
      const float* crow = c + rb * kD;
      float* orow = out + rb * kW;
      const float ev = __expf(mx[m][r] - m_tile);
      zz += ev;
#pragma unroll
      for (int n4 = 0; n4 < 4; ++n4) {
        const int d = w * 64 + n4 * 16 + lr;
        const float cvv = crow[d];
        const float pv = o[m][n4][r];
        orow[d] = cvv;
        orow[kD + d] = pv;
        orow[2 * kD + d] = cvv * pv;
        u[n4] += ev * cvv;
      }
    }
  // reduce u over lg (rows) and store; z/m once per block
#pragma unroll
  for (int n4 = 0; n4 < 4; ++n4) {
    u[n4] += __shfl_xor(u[n4], 16, 64);
    u[n4] += __shfl_xor(u[n4], 32, 64);
  }
  if (lg == 0) {
    float* ub = u_tile + ((size_t)(b * kTiles + tile)) * kD;
#pragma unroll
    for (int n4 = 0; n4 < 4; ++n4) ub[w * 64 + n4 * 16 + lr] = u[n4];
  }
  if (w == 0) {
    zz += __shfl_xor(zz, 16, 64);
    zz += __shfl_xor(zz, 32, 64);
    if (lane == 0) {
      mz[b * 64 + tile] = m_tile;
      mz[b * 64 + 32 + tile] = zz;
    }
  }
}

// q2c[b,d] = (sum_k e^{m_k-M} u_k[d]) / (sum_k e^{m_k-M} z_k)
__global__ __launch_bounds__(512) void merge_q2c_kernel(
    const float* __restrict__ mz, const float* __restrict__ u_tile,
    float* __restrict__ q2c) {
  const int b = blockIdx.x;
  const int d = threadIdx.x;
  __shared__ float sM[32], sZ[32];
  if (d < 32) {
    sM[d] = mz[b * 64 + d];
    sZ[d] = mz[b * 64 + 32 + d];
  }
  __syncthreads();
  float M = sM[0];
#pragma unroll
  for (int k = 1; k < 32; ++k) M = fmaxf(M, sM[k]);
  float Z = 0.f;
  float s = 0.f;
#pragma unroll
  for (int k = 0; k < 32; ++k) {
    const float wk = __expf(sM[k] - M);
    Z += wk * sZ[k];
    s += wk * u_tile[((size_t)(b * kTiles + k)) * kD + d];
  }
  q2c[b * kD + d] = s / Z;
}

__global__ __launch_bounds__(128) void slot3_kernel(
    const float* __restrict__ c, const float* __restrict__ q2c,
    float* __restrict__ out) {
  const int row = blockIdx.x;  // b*kT + t
  const int b = row >> 11;
  const int x4 = threadIdx.x * 4;
  f32x4 cv = *(const f32x4*)(c + (size_t)row * kD + x4);
  f32x4 qc = *(const f32x4*)(q2c + b * kD + x4);
  *(f32x4*)(out + (size_t)row * kW + 3 * kD + x4) = cv * qc;
}

extern "C" void kernel_launch(void* const* d_in, const int* in_sizes, int n_in,
                              void* d_out, int out_size, void* d_ws, size_t ws_size,
                              hipStream_t stream) {
  const float* c    = (const float*)d_in[0];
  const float* q    = (const float*)d_in[1];
  const float* w_c  = (const float*)d_in[2];
  const float* b_c  = (const float*)d_in[3];
  const float* w_q  = (const float*)d_in[4];
  const float* b_q  = (const float*)d_in[5];
  const float* w_cq = (const float*)d_in[6];
  const float* b_cq = (const float*)d_in[7];
  float* out = (float*)d_out;
  float* ws = (float*)d_ws;

  // ws layout (floats): sq 4096 | q2c 512*8 | mz 512 | u_tile 131072 ;
  // then bf16: qf 2M | vf 2M   (~9 MB total)
  float* sq     = ws;
  float* q2c    = sq + kB * kI;
  float* mz     = q2c + kB * kD;
  float* u_tile = mz + kB * 64;
  __bf16* qf = (__bf16*)(u_tile + (size_t)kB * kTiles * kD);
  __bf16* vf = qf + (size_t)kB * kI * kD;

  dim3 gpq(kI / 16, kB);
  prep_qf_kernel<<<gpq, 256, 0, stream>>>(q, w_q, b_q, sq, qf);
  dim3 gpv(kI / 64, kD / 64, kB);
  prep_vf_kernel<<<gpv, 256, 0, stream>>>(q, vf);

  dim3 gf(kTiles, kB);  // 32 x 8 = 256 blocks
  fused_attn<<<gf, 512, 0, stream>>>(c, qf, vf, w_cq, w_c, b_c, b_cq, sq, out,
                                     mz, u_tile);

  merge_q2c_kernel<<<kB, 512, 0, stream>>>(mz, u_tile, q2c);
  slot3_kernel<<<kB * kT, 128, 0, stream>>>(c, q2c, out);
}